// Round 1
// baseline (62587.756 us; speedup 1.0000x reference)
//
#include <hip/hip_runtime.h>
#include <stddef.h>

// Problem dims (fixed by the reference)
#define BB 256   // batch
#define TT 512   // time steps
#define DD 128   // input/output dim
#define HH 256   // hidden size

__device__ __forceinline__ float sigm(float x)  { return 1.0f / (1.0f + __expf(-x)); }
__device__ __forceinline__ float tanh_(float x) { return 2.0f / (1.0f + __expf(-2.0f * x)) - 1.0f; }

// One LSTM cell evaluation.
// Block = hidden unit j (grid HH), thread = batch b (block BB).
// Gate rows (PyTorch order): i=j, f=HH+j, g=2HH+j, o=3HH+j.
// XMODE 0: x from input tensor x[b][t][k]  (K1 = DD)
// XMODE 1: x from transposed buffer xs[k*BB + b]
// States h/c stored transposed [unit][batch] for coalescing.
template<int K1, int XMODE>
__global__ __launch_bounds__(BB) void cell_kernel(
    const float* __restrict__ xsrc, int t,
    const float* __restrict__ hin, const float* __restrict__ cin,
    const float* __restrict__ Wih, const float* __restrict__ Whh,
    const float* __restrict__ bih, const float* __restrict__ bhh,
    float* __restrict__ hout, float* __restrict__ cout_)
{
    const int j = blockIdx.x;   // hidden unit (uniform across block -> scalar weight loads)
    const int b = threadIdx.x;  // batch element

    float a0 = bih[j]        + bhh[j];
    float a1 = bih[HH + j]   + bhh[HH + j];
    float a2 = bih[2*HH + j] + bhh[2*HH + j];
    float a3 = bih[3*HH + j] + bhh[3*HH + j];

    const float* __restrict__ wi0 = Wih + (size_t)(0*HH + j) * K1;
    const float* __restrict__ wi1 = Wih + (size_t)(1*HH + j) * K1;
    const float* __restrict__ wi2 = Wih + (size_t)(2*HH + j) * K1;
    const float* __restrict__ wi3 = Wih + (size_t)(3*HH + j) * K1;

    #pragma unroll 4
    for (int k = 0; k < K1; ++k) {
        float xv = (XMODE == 0) ? xsrc[(size_t)b * TT * DD + (size_t)t * DD + k]
                                : xsrc[k * BB + b];
        a0 = fmaf(xv, wi0[k], a0);
        a1 = fmaf(xv, wi1[k], a1);
        a2 = fmaf(xv, wi2[k], a2);
        a3 = fmaf(xv, wi3[k], a3);
    }

    const float* __restrict__ wh0 = Whh + (size_t)(0*HH + j) * HH;
    const float* __restrict__ wh1 = Whh + (size_t)(1*HH + j) * HH;
    const float* __restrict__ wh2 = Whh + (size_t)(2*HH + j) * HH;
    const float* __restrict__ wh3 = Whh + (size_t)(3*HH + j) * HH;

    #pragma unroll 4
    for (int k = 0; k < HH; ++k) {
        float hv = hin[k * BB + b];
        a0 = fmaf(hv, wh0[k], a0);
        a1 = fmaf(hv, wh1[k], a1);
        a2 = fmaf(hv, wh2[k], a2);
        a3 = fmaf(hv, wh3[k], a3);
    }

    float ig = sigm(a0);
    float fg = sigm(a1);
    float gg = tanh_(a2);
    float og = sigm(a3);

    float cn = fg * cin[j * BB + b] + ig * gg;
    cout_[j * BB + b] = cn;
    hout[j * BB + b]  = og * tanh_(cn);
}

// y = h2 @ fc_W^T + fc_b ; write feedback buffer (transposed) + final output [B,T,D]
__global__ __launch_bounds__(BB) void fc_kernel(
    const float* __restrict__ h2, const float* __restrict__ W,
    const float* __restrict__ bias, float* __restrict__ ybuf,
    float* __restrict__ out, int t)
{
    const int d = blockIdx.x;   // output dim (uniform -> scalar weight loads)
    const int b = threadIdx.x;  // batch

    float acc = bias[d];
    const float* __restrict__ w = W + (size_t)d * HH;
    #pragma unroll 4
    for (int j = 0; j < HH; ++j)
        acc = fmaf(h2[j * BB + b], w[j], acc);

    ybuf[d * BB + b] = acc;
    out[(size_t)b * TT * DD + (size_t)t * DD + d] = acc;
}

__global__ __launch_bounds__(256) void zero_kernel(float* __restrict__ p, int n)
{
    int i = blockIdx.x * 256 + threadIdx.x;
    if (i < n) p[i] = 0.0f;
}

extern "C" void kernel_launch(void* const* d_in, const int* in_sizes, int n_in,
                              void* d_out, int out_size, void* d_ws, size_t ws_size,
                              hipStream_t stream)
{
    const float* x       = (const float*)d_in[0];
    const float* e_Wih0  = (const float*)d_in[1];
    const float* e_Whh0  = (const float*)d_in[2];
    const float* e_bih0  = (const float*)d_in[3];
    const float* e_bhh0  = (const float*)d_in[4];
    const float* e_Wih1  = (const float*)d_in[5];
    const float* e_Whh1  = (const float*)d_in[6];
    const float* e_bih1  = (const float*)d_in[7];
    const float* e_bhh1  = (const float*)d_in[8];
    const float* d_Wih0  = (const float*)d_in[9];
    const float* d_Whh0  = (const float*)d_in[10];
    const float* d_bih0  = (const float*)d_in[11];
    const float* d_bhh0  = (const float*)d_in[12];
    const float* d_Wih1  = (const float*)d_in[13];
    const float* d_Whh1  = (const float*)d_in[14];
    const float* d_bih1  = (const float*)d_in[15];
    const float* d_bhh1  = (const float*)d_in[16];
    const float* fc_W    = (const float*)d_in[17];
    const float* fc_b    = (const float*)d_in[18];

    float* out = (float*)d_out;

    // Workspace layout (floats), all transposed [unit][batch]:
    //   h1 ping/pong : 2 * HH*BB
    //   h2 ping/pong : 2 * HH*BB
    //   c1, c2       : HH*BB each
    //   y feedback   : DD*BB
    float* ws   = (float*)d_ws;
    const int S = HH * BB;              // 65536
    float* h1[2] = { ws + 0 * S, ws + 1 * S };
    float* h2[2] = { ws + 2 * S, ws + 3 * S };
    float* c1    = ws + 4 * S;
    float* c2    = ws + 5 * S;
    float* ybuf  = ws + 6 * S;          // DD*BB = 32768 floats
    const int total_state = 6 * S + DD * BB;   // 425984 floats

    // Zero-init all recurrent state + y feedback (d_ws is poisoned before every call)
    zero_kernel<<<(total_state + 255) / 256, 256, 0, stream>>>(ws, total_state);

    // ---------------- encoder ----------------
    for (int t = 0; t < TT; ++t) {
        const int pr = t & 1, pw = 1 - pr;
        // layer 0: input = x[:, t, :]
        cell_kernel<DD, 0><<<HH, BB, 0, stream>>>(
            x, t, h1[pr], c1, e_Wih0, e_Whh0, e_bih0, e_bhh0, h1[pw], c1);
        // layer 1: input = h1_new
        cell_kernel<HH, 1><<<HH, BB, 0, stream>>>(
            h1[pw], 0, h2[pr], c2, e_Wih1, e_Whh1, e_bih1, e_bhh1, h2[pw], c2);
    }
    // After 512 steps the final states sit in parity 0 (last write: pr=1 -> pw=0),
    // which is exactly what the decoder's s=0 (pr = s&1 = 0) reads.

    // ---------------- decoder (autoregressive) ----------------
    for (int s = 0; s < TT; ++s) {
        const int pr = s & 1, pw = 1 - pr;
        // layer 0: input = y feedback (zeros for s=0)
        cell_kernel<DD, 1><<<HH, BB, 0, stream>>>(
            ybuf, 0, h1[pr], c1, d_Wih0, d_Whh0, d_bih0, d_bhh0, h1[pw], c1);
        // layer 1: input = h1_new
        cell_kernel<HH, 1><<<HH, BB, 0, stream>>>(
            h1[pw], 0, h2[pr], c2, d_Wih1, d_Whh1, d_bih1, d_bhh1, h2[pw], c2);
        // fc: y = h2_new @ fc_W^T + fc_b ; write feedback + output[b][s][d]
        fc_kernel<<<DD, BB, 0, stream>>>(h2[pw], fc_W, fc_b, ybuf, out, s);
    }
}